// Round 2
// baseline (38126.208 us; speedup 1.0000x reference)
//
#include <hip/hip_runtime.h>
#include <hip/hip_fp16.h>
#include <hip/hip_cooperative_groups.h>

namespace cg = cooperative_groups;

#define B_  64
#define T_  512
#define D_  512
#define H_  1024
#define ZC_ 4096   // 4*H
#define K_  1536   // D + H

typedef _Float16 f16;
typedef __attribute__((ext_vector_type(8))) _Float16 f16x8;
typedef __attribute__((ext_vector_type(4))) float   f32x4;

// ---------------------------------------------------------------------------
// Kernel 1: zero h-buffer bank0 + bank1 + c-buffer (contiguous 512 KB region)
// ---------------------------------------------------------------------------
__global__ void init_state(uint4* __restrict__ p, int n16) {
    int i = blockIdx.x * blockDim.x + threadIdx.x;
    if (i < n16) p[i] = make_uint4(0u, 0u, 0u, 0u);
}

// ---------------------------------------------------------------------------
// Kernel 2: build Wt[c][k] (f16, column-major weights): k<512 -> Wi[k][c],
// k>=512 -> Wh[k-512][c].  Tiled LDS transpose, coalesced both sides.
// grid = (ZC_/64, K_/64), block = 256
// ---------------------------------------------------------------------------
__global__ void build_wt(const float* __restrict__ Wi, const float* __restrict__ Wh,
                         f16* __restrict__ Wt) {
    __shared__ float lds[64][65];
    const int ci = blockIdx.x;   // 0..63   (column tile)
    const int ki = blockIdx.y;   // 0..23   (k tile)
    const int tx = threadIdx.x & 63;
    const int ty = threadIdx.x >> 6;   // 0..3

    #pragma unroll
    for (int r = 0; r < 16; ++r) {
        int kk = ki * 64 + ty * 16 + r;
        int c  = ci * 64 + tx;
        float v = (kk < D_) ? Wi[(size_t)kk * ZC_ + c]
                            : Wh[(size_t)(kk - D_) * ZC_ + c];
        lds[ty * 16 + r][tx] = v;
    }
    __syncthreads();
    #pragma unroll
    for (int r = 0; r < 16; ++r) {
        int c_local = ty * 16 + r;
        int c  = ci * 64 + c_local;
        int kk = ki * 64 + tx;
        Wt[(size_t)c * K_ + kk] = (f16)lds[tx][c_local];
    }
}

// ---------------------------------------------------------------------------
// Kernel 3: LSTM step-span kernel. 256 blocks x 256 threads (4 waves).
// Block (mg, ng): batches mg*16..+15, h-cols ng*16..+15.
// Wave q computes gate q's 16x16 z-tile with K=1536 (48 MFMAs).
// Runs either as ONE cooperative launch over [0,T) with grid.sync between
// steps, or as T regular launches of a single step (t1 == t0+1, no sync).
// Cell state lives in a register, backed by global cbuf across launches.
// ---------------------------------------------------------------------------
__global__ __launch_bounds__(256, 1) void lstm_span(
    const float* __restrict__ x,   // [B][T][D] f32
    const f16* __restrict__ Wt,    // [4096][1536] f16 (column-major weights)
    const float* __restrict__ bias,// [4096] f32
    f16* __restrict__ hbuf,        // [2][B][H] f16
    float* __restrict__ cbuf,      // [B][H] f32
    float* __restrict__ out,       // [B][T][H] f32
    int t0, int t1)
{
    // XCD-aware mapping: the 4 mg-blocks sharing W columns (same ng) land on
    // the same XCD (blockIdx % 8 round-robin heuristic). Bijective over 256.
    const int bid  = blockIdx.x;
    const int xcd  = bid & 7;
    const int slot = bid >> 3;               // 0..31
    const int ng   = xcd * 8 + (slot >> 2);  // 0..63
    const int mg   = slot & 3;               // 0..3

    const int tid  = threadIdx.x;
    const int wave = tid >> 6;               // 0..3 == gate index
    const int lane = tid & 63;

    __shared__ __align__(16) f16 Alds[16][K_ + 8];  // pitch 1544 f16 (3088 B)
    __shared__ float zlds[4][16][17];               // [gate][row][col]

    const int jj = tid & 15;
    const int bl = tid >> 4;                 // 0..15 (batch row for gate phase)
    const float bi  = bias[0 * H_ + ng * 16 + jj];
    const float bff = bias[1 * H_ + ng * 16 + jj];
    const float bg  = bias[2 * H_ + ng * 16 + jj];
    const float bo  = bias[3 * H_ + ng * 16 + jj];

    // B-fragment base: column = wave*H + ng*16 + (lane&15), k-offset (lane>>4)*8
    const f16* Wcol = Wt + (size_t)(wave * H_ + ng * 16 + (lane & 15)) * K_
                         + ((lane >> 4) * 8);
    const int arow  = lane & 15;
    const int akoff = (lane >> 4) * 8;
    const int b0    = mg * 16;

    // cell state: one (batch, col) cell per thread, in a register
    const size_t cidx = (size_t)(b0 + bl) * H_ + ng * 16 + jj;
    float c = cbuf[cidx];

    cg::grid_group grid = cg::this_grid();

    for (int t = t0; t < t1; ++t) {
        const f16* hprev = hbuf + (size_t)(t & 1) * (B_ * H_);

        // ---- stage A = [x_t (f32->f16) | h_prev] rows b0..b0+15 into LDS
        // 16 rows * 192 8-elem chunks = 3072 chunks, 12 per thread
        #pragma unroll
        for (int i = 0; i < 12; ++i) {
            int ch  = tid + i * 256;
            int row = ch / 192;
            int kc  = (ch - row * 192) * 8;
            if (kc < D_) {
                const float* src = x + ((size_t)(b0 + row) * T_ + t) * D_ + kc;
                float4 v0 = ((const float4*)src)[0];
                float4 v1 = ((const float4*)src)[1];
                f16x8 o;
                o[0] = (f16)v0.x; o[1] = (f16)v0.y; o[2] = (f16)v0.z; o[3] = (f16)v0.w;
                o[4] = (f16)v1.x; o[5] = (f16)v1.y; o[6] = (f16)v1.z; o[7] = (f16)v1.w;
                *(f16x8*)(&Alds[row][kc]) = o;
            } else {
                *(uint4*)(&Alds[row][kc]) =
                    *(const uint4*)(hprev + (size_t)(b0 + row) * H_ + (kc - D_));
            }
        }
        __syncthreads();

        // ---- GEMM: 16x16 tile, K=1536, 4 independent accumulators for ILP
        f32x4 acc0 = {0,0,0,0}, acc1 = {0,0,0,0}, acc2 = {0,0,0,0}, acc3 = {0,0,0,0};
        #pragma unroll
        for (int ks = 0; ks < 48; ks += 4) {
            f16x8 a0 = *(const f16x8*)(&Alds[arow][akoff + (ks + 0) * 32]);
            f16x8 w0 = *(const f16x8*)(Wcol + (size_t)(ks + 0) * 32);
            acc0 = __builtin_amdgcn_mfma_f32_16x16x32_f16(a0, w0, acc0, 0, 0, 0);
            f16x8 a1 = *(const f16x8*)(&Alds[arow][akoff + (ks + 1) * 32]);
            f16x8 w1 = *(const f16x8*)(Wcol + (size_t)(ks + 1) * 32);
            acc1 = __builtin_amdgcn_mfma_f32_16x16x32_f16(a1, w1, acc1, 0, 0, 0);
            f16x8 a2 = *(const f16x8*)(&Alds[arow][akoff + (ks + 2) * 32]);
            f16x8 w2 = *(const f16x8*)(Wcol + (size_t)(ks + 2) * 32);
            acc2 = __builtin_amdgcn_mfma_f32_16x16x32_f16(a2, w2, acc2, 0, 0, 0);
            f16x8 a3 = *(const f16x8*)(&Alds[arow][akoff + (ks + 3) * 32]);
            f16x8 w3 = *(const f16x8*)(Wcol + (size_t)(ks + 3) * 32);
            acc3 = __builtin_amdgcn_mfma_f32_16x16x32_f16(a3, w3, acc3, 0, 0, 0);
        }
        f32x4 z = (acc0 + acc1) + (acc2 + acc3);

        // ---- C/D layout: col = lane&15, row = (lane>>4)*4 + r
        #pragma unroll
        for (int r = 0; r < 4; ++r)
            zlds[wave][(lane >> 4) * 4 + r][lane & 15] = z[r];
        __syncthreads();

        // ---- fused gates + state update; thread -> (bl, jj)
        {
            float zi = zlds[0][bl][jj] + bi;
            float zf = zlds[1][bl][jj] + bff;
            float zg = zlds[2][bl][jj] + bg;
            float zo = zlds[3][bl][jj] + bo;
            float ig = 1.f / (1.f + __expf(-zi));
            float fg = 1.f / (1.f + __expf(-zf));
            float gg = 2.f / (1.f + __expf(-2.f * zg)) - 1.f;
            float og = 1.f / (1.f + __expf(-zo));
            float nc = fg * c + ig * gg;
            float th = 2.f / (1.f + __expf(-2.f * nc)) - 1.f;
            float nh = og * th;
            c = nc;
            const int bglob = b0 + bl;
            const int col   = ng * 16 + jj;
            hbuf[(size_t)((t + 1) & 1) * (B_ * H_) + (size_t)bglob * H_ + col] = (f16)nh;
            out[((size_t)bglob * T_ + t) * H_ + col] = nh;
        }

        if (t + 1 < t1) {          // persistent mode only
            __threadfence();       // release h writes (cross-XCD)
            grid.sync();
            __threadfence();       // acquire before reading next h
        }
    }
    cbuf[cidx] = c;                // persist cell state across span launches
}

// ---------------------------------------------------------------------------
extern "C" void kernel_launch(void* const* d_in, const int* in_sizes, int n_in,
                              void* d_out, int out_size, void* d_ws, size_t ws_size,
                              hipStream_t stream) {
    const float* x    = (const float*)d_in[0];
    const float* Wi   = (const float*)d_in[1];
    const float* Wh   = (const float*)d_in[2];
    const float* bias = (const float*)d_in[3];
    float* out = (float*)d_out;

    // workspace layout (16B aligned): Wt | hbuf(2 banks) | cbuf
    const size_t wt_bytes = (size_t)ZC_ * K_ * sizeof(f16);    // 12,582,912
    const size_t hb_bytes = (size_t)2 * B_ * H_ * sizeof(f16); //    262,144
    const size_t cb_bytes = (size_t)B_ * H_ * sizeof(float);   //    262,144
    if (ws_size < wt_bytes + hb_bytes + cb_bytes) return;

    f16*   Wt   = (f16*)d_ws;
    f16*   hbuf = (f16*)((char*)d_ws + wt_bytes);
    float* cbuf = (float*)((char*)d_ws + wt_bytes + hb_bytes);

    // zero hbuf (both banks) + cbuf in one sweep (contiguous 512 KB)
    const int n16 = (int)((hb_bytes + cb_bytes) / 16);
    init_state<<<(n16 + 255) / 256, 256, 0, stream>>>((uint4*)hbuf, n16);
    build_wt<<<dim3(ZC_ / 64, K_ / 64), 256, 0, stream>>>(Wi, Wh, Wt);

    int t0 = 0, t1 = T_;
    void* args[] = { (void*)&x, (void*)&Wt, (void*)&bias, (void*)&hbuf,
                     (void*)&cbuf, (void*)&out, (void*)&t0, (void*)&t1 };
    hipError_t e = hipLaunchCooperativeKernel((const void*)lstm_span,
                                              dim3(256), dim3(256), args, 0, stream);
    if (e != hipSuccess) {
        (void)hipGetLastError();   // clear error state
        // fallback: one regular launch per timestep (h/c propagate via global)
        for (int t = 0; t < T_; ++t) {
            lstm_span<<<256, 256, 0, stream>>>(x, Wt, bias, hbuf, cbuf, out, t, t + 1);
        }
    }
}

// Round 3
// 5824.121 us; speedup vs baseline: 6.5463x; 6.5463x over previous
//
#include <hip/hip_runtime.h>
#include <hip/hip_fp16.h>

#define B_  64
#define T_  512
#define D_  512
#define H_  1024
#define ZC_ 4096   // 4*H
#define K_  1536   // D + H
#define KH_ 768    // K/2 per wave

typedef _Float16 f16;
typedef __attribute__((ext_vector_type(8))) _Float16 f16x8;
typedef __attribute__((ext_vector_type(4))) float   f32x4;

// ---------------------------------------------------------------------------
// Kernel 1: zero h-buffer (2 banks) + c-buffer + barrier counters
// ---------------------------------------------------------------------------
__global__ void init_state(uint4* __restrict__ p, int n16) {
    int i = blockIdx.x * blockDim.x + threadIdx.x;
    if (i < n16) p[i] = make_uint4(0u, 0u, 0u, 0u);
}

// ---------------------------------------------------------------------------
// Kernel 2: build Wt[c][k] (f16, column-major weights): k<512 -> Wi[k][c],
// k>=512 -> Wh[k-512][c].  Tiled LDS transpose, coalesced both sides.
// ---------------------------------------------------------------------------
__global__ void build_wt(const float* __restrict__ Wi, const float* __restrict__ Wh,
                         f16* __restrict__ Wt) {
    __shared__ float lds[64][65];
    const int ci = blockIdx.x;
    const int ki = blockIdx.y;
    const int tx = threadIdx.x & 63;
    const int ty = threadIdx.x >> 6;

    #pragma unroll
    for (int r = 0; r < 16; ++r) {
        int kk = ki * 64 + ty * 16 + r;
        int c  = ci * 64 + tx;
        float v = (kk < D_) ? Wi[(size_t)kk * ZC_ + c]
                            : Wh[(size_t)(kk - D_) * ZC_ + c];
        lds[ty * 16 + r][tx] = v;
    }
    __syncthreads();
    #pragma unroll
    for (int r = 0; r < 16; ++r) {
        int c_local = ty * 16 + r;
        int c  = ci * 64 + c_local;
        int kk = ki * 64 + tx;
        Wt[(size_t)c * K_ + kk] = (f16)lds[tx][c_local];
    }
}

// ---------------------------------------------------------------------------
// Kernel 3: LSTM span. 256 blocks x 512 threads (8 waves).
// Block bid -> group g=(bid&7)>>1 (batches g*16..+15, XCD pair {2g,2g+1}),
//              ng=((bid>>3)<<1)|(bid&1) (h-cols ng*16..+15).
// Wave w: gate q=w&3, K-half kh=w>>2. W-fragment (16 cols x 768 k) lives in
// 96 VGPRs per thread, loaded once — immune to per-step L2 invalidation.
// Sync: per-group monotonic counter barrier (64 blocks), release/acquire at
// agent scope. No grid.sync, no full-grid coupling.
// ---------------------------------------------------------------------------
__global__ __launch_bounds__(512, 2) void lstm_span(
    const float* __restrict__ x,   // [B][T][D] f32
    const f16* __restrict__ Wt,    // [4096][1536] f16 (column-major weights)
    const float* __restrict__ bias,// [4096] f32
    f16* __restrict__ hbuf,        // [2][B][H] f16
    float* __restrict__ cbuf,      // [B][H] f32
    unsigned* __restrict__ cnt,    // [4] barrier counters, 256B apart
    float* __restrict__ out,       // [B][T][H] f32
    int t0, int t1)
{
    const int bid = blockIdx.x;
    const int g   = (bid & 7) >> 1;                  // batch group 0..3
    const int ng  = ((bid >> 3) << 1) | (bid & 1);   // col group 0..63

    const int tid  = threadIdx.x;
    const int wave = tid >> 6;            // 0..7
    const int lane = tid & 63;
    const int q    = wave & 3;            // gate
    const int kh   = wave >> 2;           // K-half

    __shared__ __align__(16) f16 Alds[16][K_ + 8];   // pitch 1544 f16
    __shared__ float zlds[8][16][17];                // [wave][row][col]

    const int jj = tid & 15;
    const int bl = tid >> 4;              // valid gate-thread row when tid<256
    const float bi  = bias[0 * H_ + ng * 16 + jj];
    const float bff = bias[1 * H_ + ng * 16 + jj];
    const float bg  = bias[2 * H_ + ng * 16 + jj];
    const float bo  = bias[3 * H_ + ng * 16 + jj];

    const int arow  = lane & 15;
    const int akoff = (lane >> 4) * 8;
    const int kbase = kh * KH_ + akoff;
    const int b0    = g * 16;

    // ---- W fragment -> registers (once). col = q*H + ng*16 + (lane&15)
    const f16* Wcol = Wt + (size_t)(q * H_ + ng * 16 + (lane & 15)) * K_ + kbase;
    f16x8 wreg[24];
    #pragma unroll
    for (int ks = 0; ks < 24; ++ks)
        wreg[ks] = *(const f16x8*)(Wcol + ks * 32);

    // cell state: one (batch,col) per thread (gate threads tid<256 only)
    const size_t cidx = (size_t)(b0 + (bl & 15)) * H_ + ng * 16 + jj;
    float c = (tid < 256) ? cbuf[cidx] : 0.f;

    unsigned* mycnt = cnt + g * 64;       // 256B-spaced counters

    for (int t = t0; t < t1; ++t) {
        const f16* hprev = hbuf + (size_t)(t & 1) * (B_ * H_);

        // ---- stage A = [x_t (f32->f16) | h_prev] rows b0..b0+15 into LDS
        // 16 rows * 192 chunks(16B) = 3072 chunks, 6 per thread
        #pragma unroll
        for (int i = 0; i < 6; ++i) {
            int ch  = tid + i * 512;
            int row = ch / 192;
            int kc  = (ch - row * 192) * 8;
            if (kc < D_) {
                const float* src = x + ((size_t)(b0 + row) * T_ + t) * D_ + kc;
                float4 v0 = ((const float4*)src)[0];
                float4 v1 = ((const float4*)src)[1];
                f16x8 o;
                o[0] = (f16)v0.x; o[1] = (f16)v0.y; o[2] = (f16)v0.z; o[3] = (f16)v0.w;
                o[4] = (f16)v1.x; o[5] = (f16)v1.y; o[6] = (f16)v1.z; o[7] = (f16)v1.w;
                *(f16x8*)(&Alds[row][kc]) = o;
            } else {
                *(uint4*)(&Alds[row][kc]) =
                    *(const uint4*)(hprev + (size_t)(b0 + row) * H_ + (kc - D_));
            }
        }
        __syncthreads();

        // ---- GEMM: 16x16 tile, K-half=768, W from registers, 4-way ILP
        f32x4 acc0 = {0,0,0,0}, acc1 = {0,0,0,0}, acc2 = {0,0,0,0}, acc3 = {0,0,0,0};
        #pragma unroll
        for (int ks = 0; ks < 24; ks += 4) {
            f16x8 a0 = *(const f16x8*)(&Alds[arow][kbase + (ks + 0) * 32]);
            acc0 = __builtin_amdgcn_mfma_f32_16x16x32_f16(a0, wreg[ks + 0], acc0, 0, 0, 0);
            f16x8 a1 = *(const f16x8*)(&Alds[arow][kbase + (ks + 1) * 32]);
            acc1 = __builtin_amdgcn_mfma_f32_16x16x32_f16(a1, wreg[ks + 1], acc1, 0, 0, 0);
            f16x8 a2 = *(const f16x8*)(&Alds[arow][kbase + (ks + 2) * 32]);
            acc2 = __builtin_amdgcn_mfma_f32_16x16x32_f16(a2, wreg[ks + 2], acc2, 0, 0, 0);
            f16x8 a3 = *(const f16x8*)(&Alds[arow][kbase + (ks + 3) * 32]);
            acc3 = __builtin_amdgcn_mfma_f32_16x16x32_f16(a3, wreg[ks + 3], acc3, 0, 0, 0);
        }
        f32x4 z = (acc0 + acc1) + (acc2 + acc3);

        // ---- C/D layout: col = lane&15, row = (lane>>4)*4 + r
        #pragma unroll
        for (int r = 0; r < 4; ++r)
            zlds[wave][(lane >> 4) * 4 + r][lane & 15] = z[r];
        __syncthreads();

        // ---- fused gates + state update (threads 0..255; sum both K-halves)
        if (tid < 256) {
            float zi = zlds[0][bl][jj] + zlds[4][bl][jj] + bi;
            float zf = zlds[1][bl][jj] + zlds[5][bl][jj] + bff;
            float zg = zlds[2][bl][jj] + zlds[6][bl][jj] + bg;
            float zo = zlds[3][bl][jj] + zlds[7][bl][jj] + bo;
            float ig = 1.f / (1.f + __expf(-zi));
            float fg = 1.f / (1.f + __expf(-zf));
            float gg = 2.f / (1.f + __expf(-2.f * zg)) - 1.f;
            float og = 1.f / (1.f + __expf(-zo));
            float nc = fg * c + ig * gg;
            float th = 2.f / (1.f + __expf(-2.f * nc)) - 1.f;
            float nh = og * th;
            c = nc;
            const int bglob = b0 + bl;
            const int col   = ng * 16 + jj;
            hbuf[(size_t)((t + 1) & 1) * (B_ * H_) + (size_t)bglob * H_ + col] = (f16)nh;
            out[((size_t)bglob * T_ + t) * H_ + col] = nh;
        }

        // ---- per-group 64-block barrier (persistent mode only)
        if (t + 1 < t1) {
            __syncthreads();   // drains vmcnt: all h/out stores issued to L2
            if (tid == 0) {
                // release: acq_rel RMW at agent scope emits L2 writeback first
                __hip_atomic_fetch_add(mycnt, 1u, __ATOMIC_ACQ_REL,
                                       __HIP_MEMORY_SCOPE_AGENT);
                const unsigned target = 64u * (unsigned)(t + 1);
                while (__hip_atomic_load(mycnt, __ATOMIC_RELAXED,
                                         __HIP_MEMORY_SCOPE_AGENT) < target)
                    __builtin_amdgcn_s_sleep(2);
                __threadfence();   // acquire: invalidate stale h lines
            }
            __syncthreads();
        }
    }
    if (tid < 256) cbuf[cidx] = c;   // persist cell state across span launches
}

// ---------------------------------------------------------------------------
extern "C" void kernel_launch(void* const* d_in, const int* in_sizes, int n_in,
                              void* d_out, int out_size, void* d_ws, size_t ws_size,
                              hipStream_t stream) {
    const float* x    = (const float*)d_in[0];
    const float* Wi   = (const float*)d_in[1];
    const float* Wh   = (const float*)d_in[2];
    const float* bias = (const float*)d_in[3];
    float* out = (float*)d_out;

    // workspace: Wt | hbuf(2 banks) | cbuf | counters
    const size_t wt_bytes = (size_t)ZC_ * K_ * sizeof(f16);    // 12,582,912
    const size_t hb_bytes = (size_t)2 * B_ * H_ * sizeof(f16); //    262,144
    const size_t cb_bytes = (size_t)B_ * H_ * sizeof(float);   //    262,144
    const size_t cn_bytes = 4096;
    if (ws_size < wt_bytes + hb_bytes + cb_bytes + cn_bytes) return;

    f16*      Wt   = (f16*)d_ws;
    f16*      hbuf = (f16*)((char*)d_ws + wt_bytes);
    float*    cbuf = (float*)((char*)d_ws + wt_bytes + hb_bytes);
    unsigned* cnt  = (unsigned*)((char*)d_ws + wt_bytes + hb_bytes + cb_bytes);

    // zero hbuf + cbuf + counters (contiguous region)
    const int n16 = (int)((hb_bytes + cb_bytes + cn_bytes) / 16);
    init_state<<<(n16 + 255) / 256, 256, 0, stream>>>((uint4*)hbuf, n16);
    build_wt<<<dim3(ZC_ / 64, K_ / 64), 256, 0, stream>>>(Wi, Wh, Wt);

    int t0 = 0, t1 = T_;
    void* args[] = { (void*)&x, (void*)&Wt, (void*)&bias, (void*)&hbuf,
                     (void*)&cbuf, (void*)&cnt, (void*)&out, (void*)&t0, (void*)&t1 };
    hipError_t e = hipLaunchCooperativeKernel((const void*)lstm_span,
                                              dim3(256), dim3(512), args, 0, stream);
    if (e != hipSuccess) {
        (void)hipGetLastError();
        // fallback: one regular launch per timestep (no in-kernel barrier)
        for (int t = 0; t < T_; ++t) {
            lstm_span<<<256, 512, 0, stream>>>(x, Wt, bias, hbuf, cbuf, cnt, out, t, t + 1);
        }
    }
}

// Round 4
// 2434.064 us; speedup vs baseline: 15.6636x; 2.3928x over previous
//
#include <hip/hip_runtime.h>
#include <hip/hip_fp16.h>

#define B_  64
#define T_  512
#define D_  512
#define H_  1024
#define ZC_ 4096   // 4*H
#define K_  1536   // D + H
#define KH_ 768    // K/2 per wave

typedef _Float16 f16;
typedef __attribute__((ext_vector_type(8))) _Float16 f16x8;
typedef __attribute__((ext_vector_type(4))) float   f32x4;
typedef unsigned long long u64;

// ---------------------------------------------------------------------------
// Kernel 1: zero h-buffer (2 banks) + c-buffer + barrier counters
// ---------------------------------------------------------------------------
__global__ void init_state(uint4* __restrict__ p, int n16) {
    int i = blockIdx.x * blockDim.x + threadIdx.x;
    if (i < n16) p[i] = make_uint4(0u, 0u, 0u, 0u);
}

// ---------------------------------------------------------------------------
// Kernel 2: build Wt[c][k] (f16, column-major): k<512 -> Wi[k][c],
// k>=512 -> Wh[k-512][c].  Tiled LDS transpose, coalesced both sides.
// ---------------------------------------------------------------------------
__global__ void build_wt(const float* __restrict__ Wi, const float* __restrict__ Wh,
                         f16* __restrict__ Wt) {
    __shared__ float lds[64][65];
    const int ci = blockIdx.x;
    const int ki = blockIdx.y;
    const int tx = threadIdx.x & 63;
    const int ty = threadIdx.x >> 6;

    #pragma unroll
    for (int r = 0; r < 16; ++r) {
        int kk = ki * 64 + ty * 16 + r;
        int c  = ci * 64 + tx;
        float v = (kk < D_) ? Wi[(size_t)kk * ZC_ + c]
                            : Wh[(size_t)(kk - D_) * ZC_ + c];
        lds[ty * 16 + r][tx] = v;
    }
    __syncthreads();
    #pragma unroll
    for (int r = 0; r < 16; ++r) {
        int c_local = ty * 16 + r;
        int c  = ci * 64 + c_local;
        int kk = ki * 64 + tx;
        Wt[(size_t)c * K_ + kk] = (f16)lds[tx][c_local];
    }
}

// ---------------------------------------------------------------------------
// Kernel 3: LSTM span. 256 blocks x 512 threads (8 waves).
// Block bid -> group g=(bid&7)>>1 (batches g*16..+15, XCD pair {2g,2g+1}),
//              ng=((bid>>3)<<1)|(bid&1) (h-cols ng*16..+15).
// Wave w: gate q=w&3, K-half kh=w>>2; W fragment in 96 VGPRs, loaded once.
// h exchange: cache-bypassing relaxed AGENT atomics (sc1) -> NO L2 writeback
// or invalidate fences in the loop (L2 keeps x/out lines). Barrier is a
// per-group monotonic counter; x_{t+1} staging (waves 1-7) overlaps the spin.
// ---------------------------------------------------------------------------
__global__ __launch_bounds__(512, 2) void lstm_span(
    const float* __restrict__ x,   // [B][T][D] f32
    const f16* __restrict__ Wt,    // [4096][1536] f16 (column-major weights)
    const float* __restrict__ bias,// [4096] f32
    f16* __restrict__ hbuf,        // [2][B][H] f16 (agent-atomic access only)
    float* __restrict__ cbuf,      // [B][H] f32
    unsigned* __restrict__ cnt,    // barrier counters, 256B apart
    float* __restrict__ out,       // [B][T][H] f32
    int t0, int t1)
{
    const int bid = blockIdx.x;
    const int g   = (bid & 7) >> 1;                  // batch group 0..3
    const int ng  = ((bid >> 3) << 1) | (bid & 1);   // col group 0..63

    const int tid  = threadIdx.x;
    const int wave = tid >> 6;            // 0..7
    const int lane = tid & 63;
    const int q    = wave & 3;            // gate
    const int kh   = wave >> 2;           // K-half

    __shared__ __align__(16) f16 Alds[16][K_ + 8];   // pitch 1544 f16
    __shared__ float zlds[8][16][17];                // [wave][row][col]

    const int jj = tid & 15;
    const int bl = tid >> 4;              // gate-thread batch row when tid<256
    const float bi  = bias[0 * H_ + ng * 16 + jj];
    const float bff = bias[1 * H_ + ng * 16 + jj];
    const float bg  = bias[2 * H_ + ng * 16 + jj];
    const float bo  = bias[3 * H_ + ng * 16 + jj];

    const int arow  = lane & 15;
    const int akoff = (lane >> 4) * 8;
    const int kbase = kh * KH_ + akoff;
    const int b0    = g * 16;

    // ---- W fragment -> registers (once). col = q*H + ng*16 + (lane&15)
    const f16* Wcol = Wt + (size_t)(q * H_ + ng * 16 + (lane & 15)) * K_ + kbase;
    f16x8 wreg[24];
    #pragma unroll
    for (int ks = 0; ks < 24; ++ks)
        wreg[ks] = *(const f16x8*)(Wcol + ks * 32);

    // cell state: one (batch,col) per thread (gate threads tid<256 only)
    const size_t cidx = (size_t)(b0 + (bl & 15)) * H_ + ng * 16 + jj;
    float c = (tid < 256) ? cbuf[cidx] : 0.f;

    unsigned* mycnt = cnt + g * 64;       // 256B-spaced counters

    // ---- stage x_t slice (f32->f16) into Alds[.][0..511]; 1024 16B-chunks
    auto stage_x = [&](int t, int tbase, int nthr) {
        for (int ch = tid - tbase; ch < 1024; ch += nthr) {
            if (ch < 0) continue;
            int row = ch >> 6;
            int kc  = (ch & 63) * 8;
            const float* src = x + ((size_t)(b0 + row) * T_ + t) * D_ + kc;
            float4 v0 = ((const float4*)src)[0];
            float4 v1 = ((const float4*)src)[1];
            f16x8 o;
            o[0] = (f16)v0.x; o[1] = (f16)v0.y; o[2] = (f16)v0.z; o[3] = (f16)v0.w;
            o[4] = (f16)v1.x; o[5] = (f16)v1.y; o[6] = (f16)v1.z; o[7] = (f16)v1.w;
            *(f16x8*)(&Alds[row][kc]) = o;
        }
    };

    stage_x(t0, 0, 512);   // pre-loop: all threads stage x_{t0}

    for (int t = t0; t < t1; ++t) {
        // ---- stage h_prev (bank t&1) via cache-bypassing u64 atomic loads
        // 16 rows * 256 u64 = 4096 loads, 8 per thread
        const f16* hprev = hbuf + (size_t)(t & 1) * (B_ * H_);
        #pragma unroll
        for (int i = 0; i < 8; ++i) {
            int ch  = tid + i * 512;
            int row = ch >> 8;
            int kc  = (ch & 255) * 4;
            u64 v = __hip_atomic_load(
                (u64*)(hprev + (size_t)(b0 + row) * H_ + kc),
                __ATOMIC_RELAXED, __HIP_MEMORY_SCOPE_AGENT);
            *(u64*)(&Alds[row][D_ + kc]) = v;
        }
        __syncthreads();

        // ---- GEMM: 16x16 tile, K-half=768, W from registers, 4-way ILP
        f32x4 acc0 = {0,0,0,0}, acc1 = {0,0,0,0}, acc2 = {0,0,0,0}, acc3 = {0,0,0,0};
        #pragma unroll
        for (int ks = 0; ks < 24; ks += 4) {
            f16x8 a0 = *(const f16x8*)(&Alds[arow][kbase + (ks + 0) * 32]);
            acc0 = __builtin_amdgcn_mfma_f32_16x16x32_f16(a0, wreg[ks + 0], acc0, 0, 0, 0);
            f16x8 a1 = *(const f16x8*)(&Alds[arow][kbase + (ks + 1) * 32]);
            acc1 = __builtin_amdgcn_mfma_f32_16x16x32_f16(a1, wreg[ks + 1], acc1, 0, 0, 0);
            f16x8 a2 = *(const f16x8*)(&Alds[arow][kbase + (ks + 2) * 32]);
            acc2 = __builtin_amdgcn_mfma_f32_16x16x32_f16(a2, wreg[ks + 2], acc2, 0, 0, 0);
            f16x8 a3 = *(const f16x8*)(&Alds[arow][kbase + (ks + 3) * 32]);
            acc3 = __builtin_amdgcn_mfma_f32_16x16x32_f16(a3, wreg[ks + 3], acc3, 0, 0, 0);
        }
        f32x4 z = (acc0 + acc1) + (acc2 + acc3);

        // ---- C/D layout: col = lane&15, row = (lane>>4)*4 + r
        #pragma unroll
        for (int r = 0; r < 4; ++r)
            zlds[wave][(lane >> 4) * 4 + r][lane & 15] = z[r];
        __syncthreads();

        // ---- fused gates + state update (threads 0..255; sum both K-halves)
        if (tid < 256) {
            float zi = zlds[0][bl][jj] + zlds[4][bl][jj] + bi;
            float zf = zlds[1][bl][jj] + zlds[5][bl][jj] + bff;
            float zg = zlds[2][bl][jj] + zlds[6][bl][jj] + bg;
            float zo = zlds[3][bl][jj] + zlds[7][bl][jj] + bo;
            float ig = 1.f / (1.f + __expf(-zi));
            float fg = 1.f / (1.f + __expf(-zf));
            float gg = 2.f / (1.f + __expf(-2.f * zg)) - 1.f;
            float og = 1.f / (1.f + __expf(-zo));
            float nc = fg * c + ig * gg;
            float th = 2.f / (1.f + __expf(-2.f * nc)) - 1.f;
            float nh = og * th;
            c = nc;
            const int bglob = b0 + bl;
            const int col   = ng * 16 + jj;
            out[((size_t)bglob * T_ + t) * H_ + col] = nh;

            // pack 4 f16 h-values (jj, jj+1, jj+2, jj+3) -> one u64 agent store
            unsigned hv = (unsigned)__builtin_bit_cast(unsigned short, (f16)nh);
            unsigned h1 = __shfl_xor(hv, 1);
            unsigned h2 = __shfl_xor(hv, 2);
            unsigned h3 = __shfl_xor(hv, 3);
            if ((jj & 3) == 0) {
                u64 pk = (u64)hv | ((u64)h1 << 16) | ((u64)h2 << 32) | ((u64)h3 << 48);
                __hip_atomic_store(
                    (u64*)(hbuf + (size_t)((t + 1) & 1) * (B_ * H_)
                                + (size_t)bglob * H_ + col),
                    pk, __ATOMIC_RELAXED, __HIP_MEMORY_SCOPE_AGENT);
            }
        }

        // ---- per-group barrier; x_{t+1} staging overlaps the spin
        if (t + 1 < t1) {
            __syncthreads();   // drains vmcnt: h atomic stores are visible
            if (wave == 0) {
                if (lane == 0) {
                    __hip_atomic_fetch_add(mycnt, 1u, __ATOMIC_RELAXED,
                                           __HIP_MEMORY_SCOPE_AGENT);
                    const unsigned target = 64u * (unsigned)(t + 1);
                    while (__hip_atomic_load(mycnt, __ATOMIC_RELAXED,
                                             __HIP_MEMORY_SCOPE_AGENT) < target)
                        __builtin_amdgcn_s_sleep(2);
                }
            } else {
                stage_x(t + 1, 64, 448);   // waves 1..7 hide x staging here
            }
            __syncthreads();
        }
    }
    if (tid < 256) cbuf[cidx] = c;   // persist cell state across span launches
}

// ---------------------------------------------------------------------------
extern "C" void kernel_launch(void* const* d_in, const int* in_sizes, int n_in,
                              void* d_out, int out_size, void* d_ws, size_t ws_size,
                              hipStream_t stream) {
    const float* x    = (const float*)d_in[0];
    const float* Wi   = (const float*)d_in[1];
    const float* Wh   = (const float*)d_in[2];
    const float* bias = (const float*)d_in[3];
    float* out = (float*)d_out;

    // workspace: Wt | hbuf(2 banks) | cbuf | counters
    const size_t wt_bytes = (size_t)ZC_ * K_ * sizeof(f16);    // 12,582,912
    const size_t hb_bytes = (size_t)2 * B_ * H_ * sizeof(f16); //    262,144
    const size_t cb_bytes = (size_t)B_ * H_ * sizeof(float);   //    262,144
    const size_t cn_bytes = 4096;
    if (ws_size < wt_bytes + hb_bytes + cb_bytes + cn_bytes) return;

    f16*      Wt   = (f16*)d_ws;
    f16*      hbuf = (f16*)((char*)d_ws + wt_bytes);
    float*    cbuf = (float*)((char*)d_ws + wt_bytes + hb_bytes);
    unsigned* cnt  = (unsigned*)((char*)d_ws + wt_bytes + hb_bytes + cb_bytes);

    // zero hbuf + cbuf + counters (contiguous region)
    const int n16 = (int)((hb_bytes + cb_bytes + cn_bytes) / 16);
    init_state<<<(n16 + 255) / 256, 256, 0, stream>>>((uint4*)hbuf, n16);
    build_wt<<<dim3(ZC_ / 64, K_ / 64), 256, 0, stream>>>(Wi, Wh, Wt);

    int t0 = 0, t1 = T_;
    void* args[] = { (void*)&x, (void*)&Wt, (void*)&bias, (void*)&hbuf,
                     (void*)&cbuf, (void*)&cnt, (void*)&out, (void*)&t0, (void*)&t1 };
    hipError_t e = hipLaunchCooperativeKernel((const void*)lstm_span,
                                              dim3(256), dim3(512), args, 0, stream);
    if (e != hipSuccess) {
        (void)hipGetLastError();
        // fallback: one regular launch per timestep (no in-kernel barrier)
        for (int t = 0; t < T_; ++t) {
            lstm_span<<<256, 512, 0, stream>>>(x, Wt, bias, hbuf, cbuf, cnt, out, t, t + 1);
        }
    }
}